// Round 11
// baseline (313.713 us; speedup 1.0000x reference)
//
#include <hip/hip_runtime.h>
#include <hip/hip_bf16.h>
#include <math.h>

// Problem constants
#define BATCH 4
#define SEQ 2048
#define DMODEL 1024
#define NHEADS 16
#define DHEAD 64
#define MTOK (BATCH * SEQ)          // 8192 tokens
#define SCALE_Q 0.125f              // 1/sqrt(64)
#define NCHAIN (BATCH * NHEADS)     // 64
#define CT 64                       // chunk length (timesteps)
#define NC (SEQ / CT)               // 32 chunks per chain
#define SP 72                       // padded LDS row stride (ushorts); 144B
#define QKVS 3072                   // row stride of fused qkv buffer
#define WROWS 4224                  // wcat rows: 3072 qkv | 16 Wg | 112 zero | 1024 Wo

typedef unsigned short ushort_t;
typedef __attribute__((ext_vector_type(8))) short bf16x8;   // 8 bf16 in 4 VGPRs
typedef __attribute__((ext_vector_type(4))) float f32x4;

__device__ __forceinline__ float bf2f(unsigned short u) {
    return __uint_as_float(((unsigned)u) << 16);
}
__device__ __forceinline__ unsigned short f2bf(float f) {
    unsigned u = __float_as_uint(f);
    return (unsigned short)((u + 0x7fffu + ((u >> 16) & 1u)) >> 16);  // RNE
}

// ---------------------------------------------------------------------------
// Converts (pure bandwidth — gate GEMV lives in the QKV GEMM):
// blocks [0,8192): x row fp32->bf16.
// blocks [8192,8192+4224): wcat row r: [0,3072)=Wq|Wk|Wv, [3072,3088)=Wg,
//   [3088,3200)=zeros (MFMA pad), [3200,4224)=Wo.
// ---------------------------------------------------------------------------
__global__ __launch_bounds__(256) void cvt_all(const float* __restrict__ x,
                                               const float* __restrict__ Wq,
                                               const float* __restrict__ Wk,
                                               const float* __restrict__ Wv,
                                               const float* __restrict__ Wo,
                                               const float* __restrict__ Wg,
                                               ushort_t* __restrict__ xb,
                                               ushort_t* __restrict__ wcat) {
    const int blk = blockIdx.x;
    const int tid = threadIdx.x;

    if (blk < MTOK) {
        const float* xr = x + (size_t)blk * DMODEL;
        float4 v = ((const float4*)xr)[tid];
        ushort4 o;
        o.x = f2bf(v.x); o.y = f2bf(v.y); o.z = f2bf(v.z); o.w = f2bf(v.w);
        ((ushort4*)(xb + (size_t)blk * DMODEL))[tid] = o;
    } else {
        const int row = blk - MTOK;                  // 0..4223
        ushort4 o;
        if (row >= 3088 && row < 3200) {
            o.x = o.y = o.z = o.w = 0;
        } else {
            const float* src;
            if (row < 1024)      src = Wq + (size_t)row * DMODEL;
            else if (row < 2048) src = Wk + (size_t)(row - 1024) * DMODEL;
            else if (row < 3072) src = Wv + (size_t)(row - 2048) * DMODEL;
            else if (row < 3088) src = Wg + (size_t)(row - 3072) * DMODEL;
            else                 src = Wo + (size_t)(row - 3200) * DMODEL;
            float4 v = ((const float4*)src)[tid];
            o.x = f2bf(v.x); o.y = f2bf(v.y); o.z = f2bf(v.z); o.w = f2bf(v.w);
        }
        ((ushort4*)(wcat + (size_t)row * DMODEL))[tid] = o;
    }
}

// ---------------------------------------------------------------------------
// bf16 MFMA GEMM v3: C = ep( A[M,K] @ B[N,K]^T )
// 128x128 tile, BK=32, 16x16x32 MFMA.  A: double-buffered LDS via
// global_load_lds + XOR bank swizzle (R7-verified 0-conflict).  B: per-wave
// DIRECT global->register prefetch, one iter ahead — B fragments are
// lane-private, so LDS staging was pure overhead; the per-iter barrier now
// drains 2 DMAs (A only) instead of 4, ds_reads/iter halve to 4, GEMM LDS
// halves to 16 KB.  Duplicate B read (2 waves/band) is a same-block L2 hit.
// 2D grid (R7 config; R10's XCD swizzle cut FETCH but not dur — not binding).
// mode 0: identity -> fp32 Cf (stride N)
// mode 3: fused QKV+gate -> bf16 Cb (stride QKVS): col tiles [0,1024)
//         phi(acc*SCALE_Q), [1024,2048) phi(acc), [2048,3072) identity;
//         col tile n0==3072: gate[m][h] = sigmoid(acc + bg[h]) fp32.
// ---------------------------------------------------------------------------
#define GT 128
#define GBK 32

__global__ __launch_bounds__(256) void gemm_bf16(const ushort_t* __restrict__ A,
                                                 const ushort_t* __restrict__ B,
                                                 float* __restrict__ Cf,
                                                 ushort_t* __restrict__ Cb,
                                                 float* __restrict__ gatep,
                                                 const float* __restrict__ bgp,
                                                 int M, int N, int K,
                                                 int mode) {
    __shared__ ushort_t As[2][GT * GBK];   // 8 KB each buffer (A only)

    const int tid = threadIdx.x;
    const int w = tid >> 6;
    const int l = tid & 63;
    const int m0 = blockIdx.y * GT;
    const int n0 = blockIdx.x * GT;
    const int wm = (w >> 1) * 64;
    const int wn = (w & 1) * 64;

    // A staging: lane l -> LDS (row l>>2, slot l&3) of a 16-row segment;
    // swizzle => lane fetches global chunk (l&3) ^ ((l>>3)&3)
    const int srow = l >> 2;
    const int schunk = ((l & 3) ^ ((l >> 3) & 3)) * 8;   // elements

    const ushort_t* aseg[2];
#pragma unroll
    for (int i = 0; i < 2; ++i) {
        const int s = w * 2 + i;
        aseg[i] = A + (size_t)(m0 + s * 16 + srow) * K + schunk;
    }

#define STAGE_A(buf, k0)                                                        \
    do {                                                                        \
        _Pragma("unroll")                                                       \
        for (int i_ = 0; i_ < 2; ++i_) {                                        \
            const int s_ = w * 2 + i_;                                          \
            __builtin_amdgcn_global_load_lds(                                   \
                (const __attribute__((address_space(1))) unsigned int*)(const void*)(aseg[i_] + (k0)), \
                (__attribute__((address_space(3))) unsigned int*)(void*)&As[buf][s_ * 16 * GBK], \
                16, 0, 0);                                                      \
        }                                                                       \
    } while (0)

    f32x4 acc[4][4];
#pragma unroll
    for (int i = 0; i < 4; ++i)
#pragma unroll
        for (int j = 0; j < 4; ++j)
#pragma unroll
            for (int r = 0; r < 4; ++r) acc[i][j][r] = 0.f;

    const int fr = l & 15;
    const int fq = (l >> 4) * 8;
    // swizzled A fragment slot: logical chunk l>>4 at row ...+fr
    const int fsw = (((l >> 4) ^ ((fr >> 1) & 3))) * 8;   // elements

    // B fragment pointers (lane-private, 16B loads)
    const ushort_t* bptr[4];
#pragma unroll
    for (int tj = 0; tj < 4; ++tj)
        bptr[tj] = B + (size_t)(n0 + wn + tj * 16 + fr) * K + fq;

    bf16x8 bcur[4], bnxt[4];

    STAGE_A(0, 0);
#pragma unroll
    for (int tj = 0; tj < 4; ++tj)
        bcur[tj] = *(const bf16x8*)(bptr[tj]);

    const int nit = K / GBK;
    for (int it = 0; it < nit; ++it) {
        __syncthreads();                  // A buf[it&1] DMA landed (and bcur loads)
        if (it + 1 < nit) {
            STAGE_A((it + 1) & 1, (it + 1) * GBK);
#pragma unroll
            for (int tj = 0; tj < 4; ++tj)
                bnxt[tj] = *(const bf16x8*)(bptr[tj] + (it + 1) * GBK);
        }

        const ushort_t* __restrict__ as = As[it & 1];
        bf16x8 af[4];
#pragma unroll
        for (int ti = 0; ti < 4; ++ti)
            af[ti] = *(const bf16x8*)&as[(wm + ti * 16 + fr) * GBK + fsw];
#pragma unroll
        for (int ti = 0; ti < 4; ++ti)
#pragma unroll
            for (int tj = 0; tj < 4; ++tj)
                acc[ti][tj] = __builtin_amdgcn_mfma_f32_16x16x32_bf16(
                    af[ti], bcur[tj], acc[ti][tj], 0, 0, 0);

        if (it + 1 < nit) {
#pragma unroll
            for (int tj = 0; tj < 4; ++tj) bcur[tj] = bnxt[tj];
        }
    }
#undef STAGE_A

    const int er = (l >> 4) * 4;
    const int ec = l & 15;

    if (mode == 3 && n0 == 3072) {
        // gate tile: only cols 3072..3087 valid (wn==0, tj==0, h=ec)
#pragma unroll
        for (int ti = 0; ti < 4; ++ti)
#pragma unroll
            for (int r = 0; r < 4; ++r) {
                if (wn == 0) {
                    const int row = m0 + wm + ti * 16 + er + r;
                    const float vv = acc[ti][0][r] + bgp[ec];
                    gatep[(size_t)row * NHEADS + ec] = 1.f / (1.f + __expf(-vv));
                }
            }
        return;
    }

    // block-uniform epilogue flags
    float escale = 1.0f;
    bool do_phi = false;
    if (mode == 3) {
        do_phi = (n0 < 2048);
        escale = (n0 < 1024) ? SCALE_Q : 1.0f;
    }

#pragma unroll
    for (int ti = 0; ti < 4; ++ti)
#pragma unroll
        for (int tj = 0; tj < 4; ++tj)
#pragma unroll
            for (int r = 0; r < 4; ++r) {
                const int row = m0 + wm + ti * 16 + er + r;
                const int col = n0 + wn + tj * 16 + ec;
                float val = acc[ti][tj][r];
                if (mode == 0) {
                    Cf[(size_t)row * N + col] = val;
                } else {
                    val *= escale;
                    if (do_phi) val = (val > 0.f) ? (val + 1.f) : __expf(val);  // elu+1
                    Cb[(size_t)row * QKVS + col] = f2bf(val);
                }
            }
}

// ---------------------------------------------------------------------------
// Phase 1: per (chain, chunk) tile, decay-weighted KV outer-product sum
//   Dt[j][i] = sum_tau e^{b63 - b_tau} * v[tau][j] * k[tau][i]   (fp32)
// K',V staged FEATURE-MAJOR (transposed, decay fused into K-scatter).
// ---------------------------------------------------------------------------
__global__ __launch_bounds__(256) void p1_kernel(const ushort_t* __restrict__ qkv,
                                                 const float* __restrict__ gate,
                                                 float* __restrict__ Dt,
                                                 float* __restrict__ Bg) {
    const int tile = blockIdx.x;          // 0..2047
    const int chain = tile >> 5;
    const int c = tile & 31;
    const int b = chain >> 4;
    const int h = chain & 15;
    const int tid = threadIdx.x;
    const int w = tid >> 6;
    const int l = tid & 63;

    __shared__ ushort_t Kt[DHEAD * SP];   // Kt[i][tau], decayed
    __shared__ ushort_t Vt[DHEAD * SP];   // Vt[j][tau]
    __shared__ float bs[CT];

    const int tau = tid >> 2;
    const int seg = (tid & 3) * 16;
    const size_t grow = ((size_t)(b * SEQ + c * CT + tau)) * QKVS + h * DHEAD + seg;
    union { float4 f4[2]; ushort_t us[16]; } uk, uv;
    uk.f4[0] = *(const float4*)&qkv[grow + 1024];
    uk.f4[1] = *(const float4*)&qkv[grow + 1024 + 8];
    uv.f4[0] = *(const float4*)&qkv[grow + 2048];
    uv.f4[1] = *(const float4*)&qkv[grow + 2048 + 8];

    if (tid < 64) {
        float g = gate[((size_t)(b * SEQ + c * CT + tid)) * NHEADS + h];
        float lg = __logf(g);
#pragma unroll
        for (int d = 1; d < 64; d <<= 1) {
            float n = __shfl_up(lg, d, 64);
            if (l >= d) lg += n;
        }
        bs[tid] = lg;
        if (tid == 63) Bg[tile] = lg;
    }
    __syncthreads();

    const float e = __expf(bs[63] - bs[tau]);
#pragma unroll
    for (int f = 0; f < 16; ++f) {
        Kt[(seg + f) * SP + tau] = f2bf(e * bf2f(uk.us[f]));
        Vt[(seg + f) * SP + tau] = uv.us[f];
    }
    __syncthreads();

    const int fr = l & 15;
    const int fq = (l >> 4) * 8;
    const int jw = w * 16;

    f32x4 accD[4];
#pragma unroll
    for (int nt = 0; nt < 4; ++nt)
#pragma unroll
        for (int r = 0; r < 4; ++r) accD[nt][r] = 0.f;

#pragma unroll
    for (int kc = 0; kc < 2; ++kc) {
        bf16x8 va = *(const bf16x8*)&Vt[(jw + fr) * SP + kc * 32 + fq];
#pragma unroll
        for (int nt = 0; nt < 4; ++nt) {
            bf16x8 kf = *(const bf16x8*)&Kt[(nt * 16 + fr) * SP + kc * 32 + fq];
            accD[nt] = __builtin_amdgcn_mfma_f32_16x16x32_bf16(va, kf, accD[nt], 0, 0, 0);
        }
    }

    const int er = (l >> 4) * 4;
    const size_t dbase = (size_t)tile * (DHEAD * DHEAD);
#pragma unroll
    for (int nt = 0; nt < 4; ++nt)
#pragma unroll
        for (int r = 0; r < 4; ++r) {
            const int j = jw + er + r;
            const int i = nt * 16 + fr;
            Dt[dbase + j * DHEAD + i] = accD[nt][r];
        }
}

// ---------------------------------------------------------------------------
// Phase 2: sequential over 32 chunks; St[c] = state BEFORE chunk c (bf16,[j][i])
// ---------------------------------------------------------------------------
__global__ __launch_bounds__(256) void p2_kernel(const float* __restrict__ Dt,
                                                 const float* __restrict__ Bg,
                                                 ushort_t* __restrict__ St) {
    const int chain = blockIdx.x >> 2;
    const int jq = (blockIdx.x & 3) * 16;
    const int tid = threadIdx.x;
    const int jj = jq + (tid >> 4);
    const int ii = (tid & 15) * 4;

    float4 S = make_float4(0.f, 0.f, 0.f, 0.f);
    for (int c = 0; c < NC; ++c) {
        const size_t base = (((size_t)chain * NC + c) * DHEAD + jj) * DHEAD + ii;
        ushort4 o;
        o.x = f2bf(S.x); o.y = f2bf(S.y); o.z = f2bf(S.z); o.w = f2bf(S.w);
        *(ushort4*)&St[base] = o;
        const float eB = __expf(Bg[chain * NC + c]);
        const float4 D = *(const float4*)&Dt[base];
        S.x = eB * S.x + D.x;
        S.y = eB * S.y + D.y;
        S.z = eB * S.z + D.z;
        S.w = eB * S.w + D.w;
    }
}

// ---------------------------------------------------------------------------
// Phase 3: Y = diag(e^{b_t}) (Q@St) + (QK^T ⊙ decay ⊙ mask) @ V   -> yb bf16
// V staged feature-major; P~ LDS round-trip wave-private (no barrier).
// ---------------------------------------------------------------------------
__global__ __launch_bounds__(256) void p3_kernel(const ushort_t* __restrict__ qkv,
                                                 const ushort_t* __restrict__ St,
                                                 const float* __restrict__ gate,
                                                 ushort_t* __restrict__ yb) {
    const int tile = blockIdx.x;
    const int chain = tile >> 5;
    const int c = tile & 31;
    const int b = chain >> 4;
    const int h = chain & 15;
    const int tid = threadIdx.x;
    const int w = tid >> 6;
    const int l = tid & 63;

    __shared__ ushort_t Qs[CT * SP];
    __shared__ ushort_t Ks[CT * SP];
    __shared__ ushort_t Vt[DHEAD * SP];   // feature-major
    __shared__ ushort_t Ss[CT * SP];
    __shared__ ushort_t Ps[CT * SP];
    __shared__ float bs[CT];

    {
        const int row = tid >> 2;              // timestep tau
        const int seg = (tid & 3) * 16;
        const size_t grow = ((size_t)(b * SEQ + c * CT + row)) * QKVS + h * DHEAD + seg;
        float4 q0 = *(const float4*)&qkv[grow];
        float4 q1 = *(const float4*)&qkv[grow + 8];
        float4 k0 = *(const float4*)&qkv[grow + 1024];
        float4 k1 = *(const float4*)&qkv[grow + 1024 + 8];
        union { float4 f4[2]; ushort_t us[16]; } uv;
        uv.f4[0] = *(const float4*)&qkv[grow + 2048];
        uv.f4[1] = *(const float4*)&qkv[grow + 2048 + 8];
        const size_t srow = (((size_t)chain * NC + c) * DHEAD + row) * DHEAD + seg;
        float4 s0 = *(const float4*)&St[srow];
        float4 s1 = *(const float4*)&St[srow + 8];
        *(float4*)&Qs[row * SP + seg]     = q0;
        *(float4*)&Qs[row * SP + seg + 8] = q1;
        *(float4*)&Ks[row * SP + seg]     = k0;
        *(float4*)&Ks[row * SP + seg + 8] = k1;
        *(float4*)&Ss[row * SP + seg]     = s0;
        *(float4*)&Ss[row * SP + seg + 8] = s1;
#pragma unroll
        for (int f = 0; f < 16; ++f)
            Vt[(seg + f) * SP + row] = uv.us[f];
    }
    if (tid < 64) {
        float g = gate[((size_t)(b * SEQ + c * CT + tid)) * NHEADS + h];
        float lg = __logf(g);
#pragma unroll
        for (int d = 1; d < 64; d <<= 1) {
            float n = __shfl_up(lg, d, 64);
            if (l >= d) lg += n;
        }
        bs[tid] = lg;
    }
    __syncthreads();

    const int fr = l & 15;
    const int fq = (l >> 4) * 8;
    const int tw = w * 16;

    bf16x8 qa[2];
#pragma unroll
    for (int kc = 0; kc < 2; ++kc)
        qa[kc] = *(const bf16x8*)&Qs[(tw + fr) * SP + kc * 32 + fq];

    f32x4 accA[4], accP[4];
#pragma unroll
    for (int nt = 0; nt < 4; ++nt)
#pragma unroll
        for (int r = 0; r < 4; ++r) { accA[nt][r] = 0.f; accP[nt][r] = 0.f; }

#pragma unroll
    for (int kc = 0; kc < 2; ++kc)
#pragma unroll
        for (int nt = 0; nt < 4; ++nt) {
            bf16x8 sb = *(const bf16x8*)&Ss[(nt * 16 + fr) * SP + kc * 32 + fq];
            accA[nt] = __builtin_amdgcn_mfma_f32_16x16x32_bf16(qa[kc], sb, accA[nt], 0, 0, 0);
            bf16x8 kf = *(const bf16x8*)&Ks[(nt * 16 + fr) * SP + kc * 32 + fq];
            accP[nt] = __builtin_amdgcn_mfma_f32_16x16x32_bf16(qa[kc], kf, accP[nt], 0, 0, 0);
        }

    const int er = (l >> 4) * 4;
    int trow[4];
    float bt[4];
#pragma unroll
    for (int r = 0; r < 4; ++r) { trow[r] = tw + er + r; bt[r] = bs[trow[r]]; }
#pragma unroll
    for (int nt = 0; nt < 4; ++nt) {
        const int tau = nt * 16 + fr;
        const float btau = bs[tau];
#pragma unroll
        for (int r = 0; r < 4; ++r) {
            float f = (tau <= trow[r]) ? __expf(bt[r] - btau) : 0.f;
            Ps[trow[r] * SP + tau] = f2bf(accP[nt][r] * f);
        }
    }
    // no barrier: P~ rows are wave-private (write band == read band per wave)

    f32x4 accY[4];
#pragma unroll
    for (int r = 0; r < 4; ++r) {
        const float eb = __expf(bt[r]);
#pragma unroll
        for (int nt = 0; nt < 4; ++nt) accY[nt][r] = accA[nt][r] * eb;
    }
#pragma unroll
    for (int kc = 0; kc < 2; ++kc) {
        bf16x8 pa = *(const bf16x8*)&Ps[(tw + fr) * SP + kc * 32 + fq];
#pragma unroll
        for (int nt = 0; nt < 4; ++nt) {
            bf16x8 vf = *(const bf16x8*)&Vt[(nt * 16 + fr) * SP + kc * 32 + fq];
            accY[nt] = __builtin_amdgcn_mfma_f32_16x16x32_bf16(pa, vf, accY[nt], 0, 0, 0);
        }
    }

    const size_t ybase = ((size_t)(b * SEQ + c * CT)) * DMODEL + h * DHEAD;
#pragma unroll
    for (int nt = 0; nt < 4; ++nt)
#pragma unroll
        for (int r = 0; r < 4; ++r)
            yb[ybase + (size_t)trow[r] * DMODEL + nt * 16 + fr] = f2bf(accY[nt][r]);
}

// ---------------------------------------------------------------------------
// Host launch
// ---------------------------------------------------------------------------
extern "C" void kernel_launch(void* const* d_in, const int* in_sizes, int n_in,
                              void* d_out, int out_size, void* d_ws, size_t ws_size,
                              hipStream_t stream) {
    const float* x  = (const float*)d_in[0];
    const float* Wq = (const float*)d_in[1];
    const float* Wk = (const float*)d_in[2];
    const float* Wv = (const float*)d_in[3];
    const float* Wo = (const float*)d_in[4];
    const float* Wg = (const float*)d_in[5];
    const float* bg = (const float*)d_in[6];
    float* out = (float*)d_out;

    const size_t elems = (size_t)MTOK * DMODEL;     // 8,388,608
    const size_t stelems = (size_t)NCHAIN * NC * DHEAD * DHEAD;   // 8,388,608

    // layout with aliasing:
    // [xb | St (after p2)] [qkv] [wcat 4224 rows] [gate f32] [Bg f32] [Dt f32 | yb]
    ushort_t* xb   = (ushort_t*)d_ws;
    ushort_t* St   = xb;                            // alias: xb dead after QKV gemm
    ushort_t* qkv  = xb + elems;                    // [8192][3072]
    ushort_t* wcat = qkv + (size_t)MTOK * QKVS;
    float* gate    = (float*)(wcat + (size_t)WROWS * DMODEL);
    float* Bg      = gate + (size_t)MTOK * NHEADS;
    float* Dt      = Bg + (size_t)NCHAIN * NC;
    ushort_t* yb   = (ushort_t*)Dt;                 // alias: Dt dead after p2

    const size_t need = (size_t)((char*)(Dt + stelems) - (char*)d_ws);  // ~106 MB
    if (ws_size < need) return;

    // converts (pure bandwidth)
    cvt_all<<<dim3(MTOK + WROWS), dim3(256), 0, stream>>>(x, Wq, Wk, Wv, Wo, Wg, xb, wcat);

    // fused QKV + gate projection: 25 col tiles (24 qkv + 1 gate)
    gemm_bf16<<<dim3(25, MTOK / GT), dim3(256), 0, stream>>>(
        xb, wcat, nullptr, qkv, gate, bg, MTOK, QKVS, DMODEL, 3);

    // chunked linear-attention scan
    p1_kernel<<<dim3(NCHAIN * NC), dim3(256), 0, stream>>>(qkv, gate, Dt, Bg);
    p2_kernel<<<dim3(NCHAIN * 4), dim3(256), 0, stream>>>(Dt, Bg, St);
    p3_kernel<<<dim3(NCHAIN * NC), dim3(256), 0, stream>>>(qkv, St, gate, yb);

    // output projection (fp32 out), Wo at wcat rows [3200,4224)
    gemm_bf16<<<dim3(DMODEL / GT, MTOK / GT), dim3(256), 0, stream>>>(
        yb, wcat + (size_t)3200 * DMODEL, out, nullptr, nullptr, nullptr,
        MTOK, DMODEL, DMODEL, 0);
}

// Round 12
// 244.731 us; speedup vs baseline: 1.2819x; 1.2819x over previous
//
#include <hip/hip_runtime.h>
#include <hip/hip_bf16.h>
#include <math.h>

// Problem constants
#define BATCH 4
#define SEQ 2048
#define DMODEL 1024
#define NHEADS 16
#define DHEAD 64
#define MTOK (BATCH * SEQ)          // 8192 tokens
#define SCALE_Q 0.125f              // 1/sqrt(64)
#define NCHAIN (BATCH * NHEADS)     // 64
#define CT 64                       // chunk length (timesteps)
#define NC (SEQ / CT)               // 32 chunks per chain
#define SP 72                       // padded LDS row stride (ushorts); 144B
#define QKVS 3072                   // row stride of fused qkv buffer
#define WROWS 4224                  // wcat rows: 3072 qkv | 16 Wg | 112 zero | 1024 Wo

typedef unsigned short ushort_t;
typedef __attribute__((ext_vector_type(8))) short bf16x8;   // 8 bf16 in 4 VGPRs
typedef __attribute__((ext_vector_type(4))) float f32x4;

__device__ __forceinline__ float bf2f(unsigned short u) {
    return __uint_as_float(((unsigned)u) << 16);
}
__device__ __forceinline__ unsigned short f2bf(float f) {
    unsigned u = __float_as_uint(f);
    return (unsigned short)((u + 0x7fffu + ((u >> 16) & 1u)) >> 16);  // RNE
}

// ---------------------------------------------------------------------------
// Converts (pure bandwidth — gate GEMV lives in the QKV GEMM):
// blocks [0,8192): x row fp32->bf16.
// blocks [8192,8192+4224): wcat row r: [0,3072)=Wq|Wk|Wv, [3072,3088)=Wg,
//   [3088,3200)=zeros (MFMA pad), [3200,4224)=Wo.
// ---------------------------------------------------------------------------
__global__ __launch_bounds__(256) void cvt_all(const float* __restrict__ x,
                                               const float* __restrict__ Wq,
                                               const float* __restrict__ Wk,
                                               const float* __restrict__ Wv,
                                               const float* __restrict__ Wo,
                                               const float* __restrict__ Wg,
                                               ushort_t* __restrict__ xb,
                                               ushort_t* __restrict__ wcat) {
    const int blk = blockIdx.x;
    const int tid = threadIdx.x;

    if (blk < MTOK) {
        const float* xr = x + (size_t)blk * DMODEL;
        float4 v = ((const float4*)xr)[tid];
        ushort4 o;
        o.x = f2bf(v.x); o.y = f2bf(v.y); o.z = f2bf(v.z); o.w = f2bf(v.w);
        ((ushort4*)(xb + (size_t)blk * DMODEL))[tid] = o;
    } else {
        const int row = blk - MTOK;                  // 0..4223
        ushort4 o;
        if (row >= 3088 && row < 3200) {
            o.x = o.y = o.z = o.w = 0;
        } else {
            const float* src;
            if (row < 1024)      src = Wq + (size_t)row * DMODEL;
            else if (row < 2048) src = Wk + (size_t)(row - 1024) * DMODEL;
            else if (row < 3072) src = Wv + (size_t)(row - 2048) * DMODEL;
            else if (row < 3088) src = Wg + (size_t)(row - 3072) * DMODEL;
            else                 src = Wo + (size_t)(row - 3200) * DMODEL;
            float4 v = ((const float4*)src)[tid];
            o.x = f2bf(v.x); o.y = f2bf(v.y); o.z = f2bf(v.z); o.w = f2bf(v.w);
        }
        ((ushort4*)(wcat + (size_t)row * DMODEL))[tid] = o;
    }
}

// ---------------------------------------------------------------------------
// bf16 MFMA GEMM (R10 config — best measured total): 128x128 tile, BK=32,
// double-buffered LDS for BOTH A and B (reused operands need the dense
// DMA->LDS path; lane-private direct loads thrash L2 — R11 regression),
// XOR bank swizzle (0 conflicts — R7/R10), 16x16x32 MFMA, XCD-aware 1D grid.
// mode 0: identity -> fp32 Cf (stride N)
// mode 3: fused QKV+gate -> bf16 Cb (stride QKVS): col tiles [0,1024)
//         phi(acc*SCALE_Q), [1024,2048) phi(acc), [2048,3072) identity;
//         col tile n0==3072: gate[m][h] = sigmoid(acc + bg[h]) fp32.
// ---------------------------------------------------------------------------
#define GT 128
#define GBK 32

__global__ __launch_bounds__(256) void gemm_bf16(const ushort_t* __restrict__ A,
                                                 const ushort_t* __restrict__ B,
                                                 float* __restrict__ Cf,
                                                 ushort_t* __restrict__ Cb,
                                                 float* __restrict__ gatep,
                                                 const float* __restrict__ bgp,
                                                 int M, int N, int K,
                                                 int mode) {
    __shared__ ushort_t As[2][GT * GBK];   // 8 KB each buffer
    __shared__ ushort_t Bs[2][GT * GBK];

    const int tid = threadIdx.x;
    const int w = tid >> 6;
    const int l = tid & 63;

    // XCD swizzle: kx = XCD (blk&7) owns row-tile band [8kx,8kx+8),
    // traversed column-major (A-band stays L2-resident — R10: FETCH 71->50MB).
    const int flat = blockIdx.x;
    const int kx = flat & 7;
    const int ii = flat >> 3;
    const int bx = ii >> 3;                // col tile
    const int by = (kx << 3) | (ii & 7);   // row tile (band kx)
    const int m0 = by * GT;
    const int n0 = bx * GT;

    const int wm = (w >> 1) * 64;
    const int wn = (w & 1) * 64;

    // staging: lane l -> LDS (row l>>2, slot l&3) of a 16-row segment;
    // swizzle => lane fetches global chunk (l&3) ^ ((l>>3)&3)
    const int srow = l >> 2;
    const int schunk = ((l & 3) ^ ((l >> 3) & 3)) * 8;   // elements

    const ushort_t* aseg[2];
    const ushort_t* bseg[2];
#pragma unroll
    for (int i = 0; i < 2; ++i) {
        const int s = w * 2 + i;
        aseg[i] = A + (size_t)(m0 + s * 16 + srow) * K + schunk;
        bseg[i] = B + (size_t)(n0 + s * 16 + srow) * K + schunk;
    }

#define STAGE(buf, k0)                                                          \
    do {                                                                        \
        _Pragma("unroll")                                                       \
        for (int i_ = 0; i_ < 2; ++i_) {                                        \
            const int s_ = w * 2 + i_;                                          \
            __builtin_amdgcn_global_load_lds(                                   \
                (const __attribute__((address_space(1))) unsigned int*)(const void*)(aseg[i_] + (k0)), \
                (__attribute__((address_space(3))) unsigned int*)(void*)&As[buf][s_ * 16 * GBK], \
                16, 0, 0);                                                      \
            __builtin_amdgcn_global_load_lds(                                   \
                (const __attribute__((address_space(1))) unsigned int*)(const void*)(bseg[i_] + (k0)), \
                (__attribute__((address_space(3))) unsigned int*)(void*)&Bs[buf][s_ * 16 * GBK], \
                16, 0, 0);                                                      \
        }                                                                       \
    } while (0)

    f32x4 acc[4][4];
#pragma unroll
    for (int i = 0; i < 4; ++i)
#pragma unroll
        for (int j = 0; j < 4; ++j)
#pragma unroll
            for (int r = 0; r < 4; ++r) acc[i][j][r] = 0.f;

    const int fr = l & 15;
    // swizzled fragment slot: logical chunk c = l>>4 at row ...+fr
    const int fsw = (((l >> 4) ^ ((fr >> 1) & 3))) * 8;   // elements

    STAGE(0, 0);

    const int nit = K / GBK;
    for (int it = 0; it < nit; ++it) {
        __syncthreads();                  // buf[it&1] DMA landed; old reads done
        if (it + 1 < nit) STAGE((it + 1) & 1, (it + 1) * GBK);

        const ushort_t* __restrict__ as = As[it & 1];
        const ushort_t* __restrict__ bs = Bs[it & 1];

        bf16x8 af[4], bfr[4];
#pragma unroll
        for (int ti = 0; ti < 4; ++ti)
            af[ti] = *(const bf16x8*)&as[(wm + ti * 16 + fr) * GBK + fsw];
#pragma unroll
        for (int tj = 0; tj < 4; ++tj)
            bfr[tj] = *(const bf16x8*)&bs[(wn + tj * 16 + fr) * GBK + fsw];
#pragma unroll
        for (int ti = 0; ti < 4; ++ti)
#pragma unroll
            for (int tj = 0; tj < 4; ++tj)
                acc[ti][tj] = __builtin_amdgcn_mfma_f32_16x16x32_bf16(
                    af[ti], bfr[tj], acc[ti][tj], 0, 0, 0);
    }
#undef STAGE

    const int er = (l >> 4) * 4;
    const int ec = l & 15;

    if (mode == 3 && n0 == 3072) {
        // gate tile: only cols 3072..3087 valid (wn==0, tj==0, h=ec)
#pragma unroll
        for (int ti = 0; ti < 4; ++ti)
#pragma unroll
            for (int r = 0; r < 4; ++r) {
                if (wn == 0) {
                    const int row = m0 + wm + ti * 16 + er + r;
                    const float vv = acc[ti][0][r] + bgp[ec];
                    gatep[(size_t)row * NHEADS + ec] = 1.f / (1.f + __expf(-vv));
                }
            }
        return;
    }

    // block-uniform epilogue flags
    float escale = 1.0f;
    bool do_phi = false;
    if (mode == 3) {
        do_phi = (n0 < 2048);
        escale = (n0 < 1024) ? SCALE_Q : 1.0f;
    }

#pragma unroll
    for (int ti = 0; ti < 4; ++ti)
#pragma unroll
        for (int tj = 0; tj < 4; ++tj)
#pragma unroll
            for (int r = 0; r < 4; ++r) {
                const int row = m0 + wm + ti * 16 + er + r;
                const int col = n0 + wn + tj * 16 + ec;
                float val = acc[ti][tj][r];
                if (mode == 0) {
                    Cf[(size_t)row * N + col] = val;
                } else {
                    val *= escale;
                    if (do_phi) val = (val > 0.f) ? (val + 1.f) : __expf(val);  // elu+1
                    Cb[(size_t)row * QKVS + col] = f2bf(val);
                }
            }
}

// ---------------------------------------------------------------------------
// Phase 1: per (chain, chunk) tile, decay-weighted KV outer-product sum
//   Dt[j][i] = sum_tau e^{b63 - b_tau} * v[tau][j] * k[tau][i]   (bf16 out)
// K',V staged FEATURE-MAJOR (transposed, decay fused into K-scatter).
// ---------------------------------------------------------------------------
__global__ __launch_bounds__(256) void p1_kernel(const ushort_t* __restrict__ qkv,
                                                 const float* __restrict__ gate,
                                                 ushort_t* __restrict__ Dt,
                                                 float* __restrict__ Bg) {
    const int tile = blockIdx.x;          // 0..2047
    const int chain = tile >> 5;
    const int c = tile & 31;
    const int b = chain >> 4;
    const int h = chain & 15;
    const int tid = threadIdx.x;
    const int w = tid >> 6;
    const int l = tid & 63;

    __shared__ ushort_t Kt[DHEAD * SP];   // Kt[i][tau], decayed
    __shared__ ushort_t Vt[DHEAD * SP];   // Vt[j][tau]
    __shared__ float bs[CT];

    const int tau = tid >> 2;
    const int seg = (tid & 3) * 16;
    const size_t grow = ((size_t)(b * SEQ + c * CT + tau)) * QKVS + h * DHEAD + seg;
    union { float4 f4[2]; ushort_t us[16]; } uk, uv;
    uk.f4[0] = *(const float4*)&qkv[grow + 1024];
    uk.f4[1] = *(const float4*)&qkv[grow + 1024 + 8];
    uv.f4[0] = *(const float4*)&qkv[grow + 2048];
    uv.f4[1] = *(const float4*)&qkv[grow + 2048 + 8];

    if (tid < 64) {
        float g = gate[((size_t)(b * SEQ + c * CT + tid)) * NHEADS + h];
        float lg = __logf(g);
#pragma unroll
        for (int d = 1; d < 64; d <<= 1) {
            float n = __shfl_up(lg, d, 64);
            if (l >= d) lg += n;
        }
        bs[tid] = lg;
        if (tid == 63) Bg[tile] = lg;
    }
    __syncthreads();

    const float e = __expf(bs[63] - bs[tau]);
#pragma unroll
    for (int f = 0; f < 16; ++f) {
        Kt[(seg + f) * SP + tau] = f2bf(e * bf2f(uk.us[f]));
        Vt[(seg + f) * SP + tau] = uv.us[f];
    }
    __syncthreads();

    const int fr = l & 15;
    const int fq = (l >> 4) * 8;
    const int jw = w * 16;

    f32x4 accD[4];
#pragma unroll
    for (int nt = 0; nt < 4; ++nt)
#pragma unroll
        for (int r = 0; r < 4; ++r) accD[nt][r] = 0.f;

#pragma unroll
    for (int kc = 0; kc < 2; ++kc) {
        bf16x8 va = *(const bf16x8*)&Vt[(jw + fr) * SP + kc * 32 + fq];
#pragma unroll
        for (int nt = 0; nt < 4; ++nt) {
            bf16x8 kf = *(const bf16x8*)&Kt[(nt * 16 + fr) * SP + kc * 32 + fq];
            accD[nt] = __builtin_amdgcn_mfma_f32_16x16x32_bf16(va, kf, accD[nt], 0, 0, 0);
        }
    }

    const int er = (l >> 4) * 4;
    const size_t dbase = (size_t)tile * (DHEAD * DHEAD);
#pragma unroll
    for (int nt = 0; nt < 4; ++nt)
#pragma unroll
        for (int r = 0; r < 4; ++r) {
            const int j = jw + er + r;
            const int i = nt * 16 + fr;
            Dt[dbase + j * DHEAD + i] = f2bf(accD[nt][r]);
        }
}

// ---------------------------------------------------------------------------
// Phase 2: sequential over 32 chunks; St[c] = state BEFORE chunk c (bf16,[j][i])
// Dt now bf16 (halves intermediate traffic); accumulation stays fp32.
// ---------------------------------------------------------------------------
__global__ __launch_bounds__(256) void p2_kernel(const ushort_t* __restrict__ Dt,
                                                 const float* __restrict__ Bg,
                                                 ushort_t* __restrict__ St) {
    const int chain = blockIdx.x >> 2;
    const int jq = (blockIdx.x & 3) * 16;
    const int tid = threadIdx.x;
    const int jj = jq + (tid >> 4);
    const int ii = (tid & 15) * 4;

    float4 S = make_float4(0.f, 0.f, 0.f, 0.f);
    for (int c = 0; c < NC; ++c) {
        const size_t base = (((size_t)chain * NC + c) * DHEAD + jj) * DHEAD + ii;
        ushort4 o;
        o.x = f2bf(S.x); o.y = f2bf(S.y); o.z = f2bf(S.z); o.w = f2bf(S.w);
        *(ushort4*)&St[base] = o;
        const float eB = __expf(Bg[chain * NC + c]);
        ushort4 d4 = *(const ushort4*)&Dt[base];
        S.x = eB * S.x + bf2f(d4.x);
        S.y = eB * S.y + bf2f(d4.y);
        S.z = eB * S.z + bf2f(d4.z);
        S.w = eB * S.w + bf2f(d4.w);
    }
}

// ---------------------------------------------------------------------------
// Phase 3: Y = diag(e^{b_t}) (Q@St) + (QK^T ⊙ decay ⊙ mask) @ V   -> yb bf16
// V staged feature-major; P~ LDS round-trip wave-private (no barrier).
// ---------------------------------------------------------------------------
__global__ __launch_bounds__(256) void p3_kernel(const ushort_t* __restrict__ qkv,
                                                 const ushort_t* __restrict__ St,
                                                 const float* __restrict__ gate,
                                                 ushort_t* __restrict__ yb) {
    const int tile = blockIdx.x;
    const int chain = tile >> 5;
    const int c = tile & 31;
    const int b = chain >> 4;
    const int h = chain & 15;
    const int tid = threadIdx.x;
    const int w = tid >> 6;
    const int l = tid & 63;

    __shared__ ushort_t Qs[CT * SP];
    __shared__ ushort_t Ks[CT * SP];
    __shared__ ushort_t Vt[DHEAD * SP];   // feature-major
    __shared__ ushort_t Ss[CT * SP];
    __shared__ ushort_t Ps[CT * SP];
    __shared__ float bs[CT];

    {
        const int row = tid >> 2;              // timestep tau
        const int seg = (tid & 3) * 16;
        const size_t grow = ((size_t)(b * SEQ + c * CT + row)) * QKVS + h * DHEAD + seg;
        float4 q0 = *(const float4*)&qkv[grow];
        float4 q1 = *(const float4*)&qkv[grow + 8];
        float4 k0 = *(const float4*)&qkv[grow + 1024];
        float4 k1 = *(const float4*)&qkv[grow + 1024 + 8];
        union { float4 f4[2]; ushort_t us[16]; } uv;
        uv.f4[0] = *(const float4*)&qkv[grow + 2048];
        uv.f4[1] = *(const float4*)&qkv[grow + 2048 + 8];
        const size_t srow = (((size_t)chain * NC + c) * DHEAD + row) * DHEAD + seg;
        float4 s0 = *(const float4*)&St[srow];
        float4 s1 = *(const float4*)&St[srow + 8];
        *(float4*)&Qs[row * SP + seg]     = q0;
        *(float4*)&Qs[row * SP + seg + 8] = q1;
        *(float4*)&Ks[row * SP + seg]     = k0;
        *(float4*)&Ks[row * SP + seg + 8] = k1;
        *(float4*)&Ss[row * SP + seg]     = s0;
        *(float4*)&Ss[row * SP + seg + 8] = s1;
#pragma unroll
        for (int f = 0; f < 16; ++f)
            Vt[(seg + f) * SP + row] = uv.us[f];
    }
    if (tid < 64) {
        float g = gate[((size_t)(b * SEQ + c * CT + tid)) * NHEADS + h];
        float lg = __logf(g);
#pragma unroll
        for (int d = 1; d < 64; d <<= 1) {
            float n = __shfl_up(lg, d, 64);
            if (l >= d) lg += n;
        }
        bs[tid] = lg;
    }
    __syncthreads();

    const int fr = l & 15;
    const int fq = (l >> 4) * 8;
    const int tw = w * 16;

    bf16x8 qa[2];
#pragma unroll
    for (int kc = 0; kc < 2; ++kc)
        qa[kc] = *(const bf16x8*)&Qs[(tw + fr) * SP + kc * 32 + fq];

    f32x4 accA[4], accP[4];
#pragma unroll
    for (int nt = 0; nt < 4; ++nt)
#pragma unroll
        for (int r = 0; r < 4; ++r) { accA[nt][r] = 0.f; accP[nt][r] = 0.f; }

#pragma unroll
    for (int kc = 0; kc < 2; ++kc)
#pragma unroll
        for (int nt = 0; nt < 4; ++nt) {
            bf16x8 sb = *(const bf16x8*)&Ss[(nt * 16 + fr) * SP + kc * 32 + fq];
            accA[nt] = __builtin_amdgcn_mfma_f32_16x16x32_bf16(qa[kc], sb, accA[nt], 0, 0, 0);
            bf16x8 kf = *(const bf16x8*)&Ks[(nt * 16 + fr) * SP + kc * 32 + fq];
            accP[nt] = __builtin_amdgcn_mfma_f32_16x16x32_bf16(qa[kc], kf, accP[nt], 0, 0, 0);
        }

    const int er = (l >> 4) * 4;
    int trow[4];
    float bt[4];
#pragma unroll
    for (int r = 0; r < 4; ++r) { trow[r] = tw + er + r; bt[r] = bs[trow[r]]; }
#pragma unroll
    for (int nt = 0; nt < 4; ++nt) {
        const int tau = nt * 16 + fr;
        const float btau = bs[tau];
#pragma unroll
        for (int r = 0; r < 4; ++r) {
            float f = (tau <= trow[r]) ? __expf(bt[r] - btau) : 0.f;
            Ps[trow[r] * SP + tau] = f2bf(accP[nt][r] * f);
        }
    }
    // no barrier: P~ rows are wave-private (write band == read band per wave)

    f32x4 accY[4];
#pragma unroll
    for (int r = 0; r < 4; ++r) {
        const float eb = __expf(bt[r]);
#pragma unroll
        for (int nt = 0; nt < 4; ++nt) accY[nt][r] = accA[nt][r] * eb;
    }
#pragma unroll
    for (int kc = 0; kc < 2; ++kc) {
        bf16x8 pa = *(const bf16x8*)&Ps[(tw + fr) * SP + kc * 32 + fq];
#pragma unroll
        for (int nt = 0; nt < 4; ++nt) {
            bf16x8 vf = *(const bf16x8*)&Vt[(nt * 16 + fr) * SP + kc * 32 + fq];
            accY[nt] = __builtin_amdgcn_mfma_f32_16x16x32_bf16(pa, vf, accY[nt], 0, 0, 0);
        }
    }

    const size_t ybase = ((size_t)(b * SEQ + c * CT)) * DMODEL + h * DHEAD;
#pragma unroll
    for (int nt = 0; nt < 4; ++nt)
#pragma unroll
        for (int r = 0; r < 4; ++r)
            yb[ybase + (size_t)trow[r] * DMODEL + nt * 16 + fr] = f2bf(accY[nt][r]);
}

// ---------------------------------------------------------------------------
// Host launch
// ---------------------------------------------------------------------------
extern "C" void kernel_launch(void* const* d_in, const int* in_sizes, int n_in,
                              void* d_out, int out_size, void* d_ws, size_t ws_size,
                              hipStream_t stream) {
    const float* x  = (const float*)d_in[0];
    const float* Wq = (const float*)d_in[1];
    const float* Wk = (const float*)d_in[2];
    const float* Wv = (const float*)d_in[3];
    const float* Wo = (const float*)d_in[4];
    const float* Wg = (const float*)d_in[5];
    const float* bg = (const float*)d_in[6];
    float* out = (float*)d_out;

    const size_t elems = (size_t)MTOK * DMODEL;     // 8,388,608
    const size_t stelems = (size_t)NCHAIN * NC * DHEAD * DHEAD;   // 8,388,608

    // layout with aliasing:
    // [xb | St (after p2)] [qkv] [wcat 4224 rows] [gate f32] [Bg f32] [Dt bf16 | yb]
    ushort_t* xb   = (ushort_t*)d_ws;
    ushort_t* St   = xb;                            // alias: xb dead after QKV gemm
    ushort_t* qkv  = xb + elems;                    // [8192][3072]
    ushort_t* wcat = qkv + (size_t)MTOK * QKVS;
    float* gate    = (float*)(wcat + (size_t)WROWS * DMODEL);
    float* Bg      = gate + (size_t)MTOK * NHEADS;
    ushort_t* Dt   = (ushort_t*)(Bg + (size_t)NCHAIN * NC);
    ushort_t* yb   = Dt;                            // alias: Dt dead after p2

    const size_t need = (size_t)((char*)(Dt + stelems) - (char*)d_ws);  // ~90 MB
    if (ws_size < need) return;

    // converts (pure bandwidth)
    cvt_all<<<dim3(MTOK + WROWS), dim3(256), 0, stream>>>(x, Wq, Wk, Wv, Wo, Wg, xb, wcat);

    // fused QKV + gate projection: 25 col tiles (24 qkv + 1 gate), XCD-swizzled
    gemm_bf16<<<dim3(25 * 64), dim3(256), 0, stream>>>(
        xb, wcat, nullptr, qkv, gate, bg, MTOK, QKVS, DMODEL, 3);

    // chunked linear-attention scan
    p1_kernel<<<dim3(NCHAIN * NC), dim3(256), 0, stream>>>(qkv, gate, Dt, Bg);
    p2_kernel<<<dim3(NCHAIN * 4), dim3(256), 0, stream>>>(Dt, Bg, St);
    p3_kernel<<<dim3(NCHAIN * NC), dim3(256), 0, stream>>>(qkv, St, gate, yb);

    // output projection (fp32 out), Wo at wcat rows [3200,4224), XCD-swizzled
    gemm_bf16<<<dim3(8 * 64), dim3(256), 0, stream>>>(
        yb, wcat + (size_t)3200 * DMODEL, out, nullptr, nullptr, nullptr,
        MTOK, DMODEL, DMODEL, 0);
}

// Round 13
// 240.379 us; speedup vs baseline: 1.3051x; 1.0181x over previous
//
#include <hip/hip_runtime.h>
#include <hip/hip_bf16.h>
#include <math.h>

// Problem constants
#define BATCH 4
#define SEQ 2048
#define DMODEL 1024
#define NHEADS 16
#define DHEAD 64
#define MTOK (BATCH * SEQ)          // 8192 tokens
#define SCALE_Q 0.125f              // 1/sqrt(64)
#define NCHAIN (BATCH * NHEADS)     // 64
#define CT 64                       // chunk length (timesteps)
#define NC (SEQ / CT)               // 32 chunks per chain
#define SP 72                       // padded LDS row stride (ushorts); 144B
#define QKVS 3072                   // row stride of fused qkv buffer
#define WROWS 4224                  // wcat rows: 3072 qkv | 16 Wg | 112 zero | 1024 Wo

typedef unsigned short ushort_t;
typedef __attribute__((ext_vector_type(8))) short bf16x8;   // 8 bf16 in 4 VGPRs
typedef __attribute__((ext_vector_type(4))) float f32x4;

__device__ __forceinline__ float bf2f(unsigned short u) {
    return __uint_as_float(((unsigned)u) << 16);
}
__device__ __forceinline__ unsigned short f2bf(float f) {
    unsigned u = __float_as_uint(f);
    return (unsigned short)((u + 0x7fffu + ((u >> 16) & 1u)) >> 16);  // RNE
}

// ---------------------------------------------------------------------------
// Converts (pure bandwidth — gate GEMV lives in the QKV GEMM):
// blocks [0,8192): x row fp32->bf16.
// blocks [8192,8192+4224): wcat row r: [0,3072)=Wq|Wk|Wv, [3072,3088)=Wg,
//   [3088,3200)=zeros (MFMA pad), [3200,4224)=Wo.
// ---------------------------------------------------------------------------
__global__ __launch_bounds__(256) void cvt_all(const float* __restrict__ x,
                                               const float* __restrict__ Wq,
                                               const float* __restrict__ Wk,
                                               const float* __restrict__ Wv,
                                               const float* __restrict__ Wo,
                                               const float* __restrict__ Wg,
                                               ushort_t* __restrict__ xb,
                                               ushort_t* __restrict__ wcat) {
    const int blk = blockIdx.x;
    const int tid = threadIdx.x;

    if (blk < MTOK) {
        const float* xr = x + (size_t)blk * DMODEL;
        float4 v = ((const float4*)xr)[tid];
        ushort4 o;
        o.x = f2bf(v.x); o.y = f2bf(v.y); o.z = f2bf(v.z); o.w = f2bf(v.w);
        ((ushort4*)(xb + (size_t)blk * DMODEL))[tid] = o;
    } else {
        const int row = blk - MTOK;                  // 0..4223
        ushort4 o;
        if (row >= 3088 && row < 3200) {
            o.x = o.y = o.z = o.w = 0;
        } else {
            const float* src;
            if (row < 1024)      src = Wq + (size_t)row * DMODEL;
            else if (row < 2048) src = Wk + (size_t)(row - 1024) * DMODEL;
            else if (row < 3072) src = Wv + (size_t)(row - 2048) * DMODEL;
            else if (row < 3088) src = Wg + (size_t)(row - 3072) * DMODEL;
            else                 src = Wo + (size_t)(row - 3200) * DMODEL;
            float4 v = ((const float4*)src)[tid];
            o.x = f2bf(v.x); o.y = f2bf(v.y); o.z = f2bf(v.z); o.w = f2bf(v.w);
        }
        ((ushort4*)(wcat + (size_t)row * DMODEL))[tid] = o;
    }
}

// ---------------------------------------------------------------------------
// bf16 MFMA GEMM (R10/R12 config — best measured, reproduced): 128x128 tile,
// BK=32, double-buffered LDS for BOTH A and B (reused operands need the dense
// DMA->LDS path; lane-private direct loads thrash L2 — R11 regression),
// XOR bank swizzle (0 conflicts — R7/R10/R12), 16x16x32 MFMA, XCD-aware grid.
// Plateau note: R8 (32x32 MFMA) and R11 (B-direct) both regressed; the
// per-iter barrier vmcnt(0) drain is the structural ~40% stall (m97 plateau).
// mode 0: identity -> fp32 Cf (stride N)
// mode 3: fused QKV+gate -> bf16 Cb (stride QKVS): col tiles [0,1024)
//         phi(acc*SCALE_Q), [1024,2048) phi(acc), [2048,3072) identity;
//         col tile n0==3072: gate[m][h] = sigmoid(acc + bg[h]) fp32.
// ---------------------------------------------------------------------------
#define GT 128
#define GBK 32

__global__ __launch_bounds__(256) void gemm_bf16(const ushort_t* __restrict__ A,
                                                 const ushort_t* __restrict__ B,
                                                 float* __restrict__ Cf,
                                                 ushort_t* __restrict__ Cb,
                                                 float* __restrict__ gatep,
                                                 const float* __restrict__ bgp,
                                                 int M, int N, int K,
                                                 int mode) {
    __shared__ ushort_t As[2][GT * GBK];   // 8 KB each buffer
    __shared__ ushort_t Bs[2][GT * GBK];

    const int tid = threadIdx.x;
    const int w = tid >> 6;
    const int l = tid & 63;

    // XCD swizzle: kx = XCD (blk&7) owns row-tile band [8kx,8kx+8),
    // traversed column-major (A-band stays L2-resident — R10: FETCH 71->50MB).
    const int flat = blockIdx.x;
    const int kx = flat & 7;
    const int ii = flat >> 3;
    const int bx = ii >> 3;                // col tile
    const int by = (kx << 3) | (ii & 7);   // row tile (band kx)
    const int m0 = by * GT;
    const int n0 = bx * GT;

    const int wm = (w >> 1) * 64;
    const int wn = (w & 1) * 64;

    // staging: lane l -> LDS (row l>>2, slot l&3) of a 16-row segment;
    // swizzle => lane fetches global chunk (l&3) ^ ((l>>3)&3)
    const int srow = l >> 2;
    const int schunk = ((l & 3) ^ ((l >> 3) & 3)) * 8;   // elements

    const ushort_t* aseg[2];
    const ushort_t* bseg[2];
#pragma unroll
    for (int i = 0; i < 2; ++i) {
        const int s = w * 2 + i;
        aseg[i] = A + (size_t)(m0 + s * 16 + srow) * K + schunk;
        bseg[i] = B + (size_t)(n0 + s * 16 + srow) * K + schunk;
    }

#define STAGE(buf, k0)                                                          \
    do {                                                                        \
        _Pragma("unroll")                                                       \
        for (int i_ = 0; i_ < 2; ++i_) {                                        \
            const int s_ = w * 2 + i_;                                          \
            __builtin_amdgcn_global_load_lds(                                   \
                (const __attribute__((address_space(1))) unsigned int*)(const void*)(aseg[i_] + (k0)), \
                (__attribute__((address_space(3))) unsigned int*)(void*)&As[buf][s_ * 16 * GBK], \
                16, 0, 0);                                                      \
            __builtin_amdgcn_global_load_lds(                                   \
                (const __attribute__((address_space(1))) unsigned int*)(const void*)(bseg[i_] + (k0)), \
                (__attribute__((address_space(3))) unsigned int*)(void*)&Bs[buf][s_ * 16 * GBK], \
                16, 0, 0);                                                      \
        }                                                                       \
    } while (0)

    f32x4 acc[4][4];
#pragma unroll
    for (int i = 0; i < 4; ++i)
#pragma unroll
        for (int j = 0; j < 4; ++j)
#pragma unroll
            for (int r = 0; r < 4; ++r) acc[i][j][r] = 0.f;

    const int fr = l & 15;
    // swizzled fragment slot: logical chunk c = l>>4 at row ...+fr
    const int fsw = (((l >> 4) ^ ((fr >> 1) & 3))) * 8;   // elements

    STAGE(0, 0);

    const int nit = K / GBK;
    for (int it = 0; it < nit; ++it) {
        __syncthreads();                  // buf[it&1] DMA landed; old reads done
        if (it + 1 < nit) STAGE((it + 1) & 1, (it + 1) * GBK);

        const ushort_t* __restrict__ as = As[it & 1];
        const ushort_t* __restrict__ bs = Bs[it & 1];

        bf16x8 af[4], bfr[4];
#pragma unroll
        for (int ti = 0; ti < 4; ++ti)
            af[ti] = *(const bf16x8*)&as[(wm + ti * 16 + fr) * GBK + fsw];
#pragma unroll
        for (int tj = 0; tj < 4; ++tj)
            bfr[tj] = *(const bf16x8*)&bs[(wn + tj * 16 + fr) * GBK + fsw];
#pragma unroll
        for (int ti = 0; ti < 4; ++ti)
#pragma unroll
            for (int tj = 0; tj < 4; ++tj)
                acc[ti][tj] = __builtin_amdgcn_mfma_f32_16x16x32_bf16(
                    af[ti], bfr[tj], acc[ti][tj], 0, 0, 0);
    }
#undef STAGE

    const int er = (l >> 4) * 4;
    const int ec = l & 15;

    if (mode == 3 && n0 == 3072) {
        // gate tile: only cols 3072..3087 valid (wn==0, tj==0, h=ec)
#pragma unroll
        for (int ti = 0; ti < 4; ++ti)
#pragma unroll
            for (int r = 0; r < 4; ++r) {
                if (wn == 0) {
                    const int row = m0 + wm + ti * 16 + er + r;
                    const float vv = acc[ti][0][r] + bgp[ec];
                    gatep[(size_t)row * NHEADS + ec] = 1.f / (1.f + __expf(-vv));
                }
            }
        return;
    }

    // block-uniform epilogue flags
    float escale = 1.0f;
    bool do_phi = false;
    if (mode == 3) {
        do_phi = (n0 < 2048);
        escale = (n0 < 1024) ? SCALE_Q : 1.0f;
    }

#pragma unroll
    for (int ti = 0; ti < 4; ++ti)
#pragma unroll
        for (int tj = 0; tj < 4; ++tj)
#pragma unroll
            for (int r = 0; r < 4; ++r) {
                const int row = m0 + wm + ti * 16 + er + r;
                const int col = n0 + wn + tj * 16 + ec;
                float val = acc[ti][tj][r];
                if (mode == 0) {
                    Cf[(size_t)row * N + col] = val;
                } else {
                    val *= escale;
                    if (do_phi) val = (val > 0.f) ? (val + 1.f) : __expf(val);  // elu+1
                    Cb[(size_t)row * QKVS + col] = f2bf(val);
                }
            }
}

// ---------------------------------------------------------------------------
// Phase 1: per (chain, chunk) tile, decay-weighted KV outer-product sum
//   Dt[j][i] = sum_tau e^{b63 - b_tau} * v[tau][j] * k[tau][i]   (bf16 out)
// K',V staged FEATURE-MAJOR (transposed, decay fused into K-scatter).
// ---------------------------------------------------------------------------
__global__ __launch_bounds__(256) void p1_kernel(const ushort_t* __restrict__ qkv,
                                                 const float* __restrict__ gate,
                                                 ushort_t* __restrict__ Dt,
                                                 float* __restrict__ Bg) {
    const int tile = blockIdx.x;          // 0..2047
    const int chain = tile >> 5;
    const int c = tile & 31;
    const int b = chain >> 4;
    const int h = chain & 15;
    const int tid = threadIdx.x;
    const int w = tid >> 6;
    const int l = tid & 63;

    __shared__ ushort_t Kt[DHEAD * SP];   // Kt[i][tau], decayed
    __shared__ ushort_t Vt[DHEAD * SP];   // Vt[j][tau]
    __shared__ float bs[CT];

    const int tau = tid >> 2;
    const int seg = (tid & 3) * 16;
    const size_t grow = ((size_t)(b * SEQ + c * CT + tau)) * QKVS + h * DHEAD + seg;
    union { float4 f4[2]; ushort_t us[16]; } uk, uv;
    uk.f4[0] = *(const float4*)&qkv[grow + 1024];
    uk.f4[1] = *(const float4*)&qkv[grow + 1024 + 8];
    uv.f4[0] = *(const float4*)&qkv[grow + 2048];
    uv.f4[1] = *(const float4*)&qkv[grow + 2048 + 8];

    if (tid < 64) {
        float g = gate[((size_t)(b * SEQ + c * CT + tid)) * NHEADS + h];
        float lg = __logf(g);
#pragma unroll
        for (int d = 1; d < 64; d <<= 1) {
            float n = __shfl_up(lg, d, 64);
            if (l >= d) lg += n;
        }
        bs[tid] = lg;
        if (tid == 63) Bg[tile] = lg;
    }
    __syncthreads();

    const float e = __expf(bs[63] - bs[tau]);
#pragma unroll
    for (int f = 0; f < 16; ++f) {
        Kt[(seg + f) * SP + tau] = f2bf(e * bf2f(uk.us[f]));
        Vt[(seg + f) * SP + tau] = uv.us[f];
    }
    __syncthreads();

    const int fr = l & 15;
    const int fq = (l >> 4) * 8;
    const int jw = w * 16;

    f32x4 accD[4];
#pragma unroll
    for (int nt = 0; nt < 4; ++nt)
#pragma unroll
        for (int r = 0; r < 4; ++r) accD[nt][r] = 0.f;

#pragma unroll
    for (int kc = 0; kc < 2; ++kc) {
        bf16x8 va = *(const bf16x8*)&Vt[(jw + fr) * SP + kc * 32 + fq];
#pragma unroll
        for (int nt = 0; nt < 4; ++nt) {
            bf16x8 kf = *(const bf16x8*)&Kt[(nt * 16 + fr) * SP + kc * 32 + fq];
            accD[nt] = __builtin_amdgcn_mfma_f32_16x16x32_bf16(va, kf, accD[nt], 0, 0, 0);
        }
    }

    const int er = (l >> 4) * 4;
    const size_t dbase = (size_t)tile * (DHEAD * DHEAD);
#pragma unroll
    for (int nt = 0; nt < 4; ++nt)
#pragma unroll
        for (int r = 0; r < 4; ++r) {
            const int j = jw + er + r;
            const int i = nt * 16 + fr;
            Dt[dbase + j * DHEAD + i] = f2bf(accD[nt][r]);
        }
}

// ---------------------------------------------------------------------------
// Phase 2: sequential over 32 chunks; St[c] = state BEFORE chunk c (bf16,[j][i])
// Latency fix: the 32 chunk loads are INDEPENDENT of the serial S-chain —
// issue them ALL up front (64 VGPRs of data; 1 block/CU so registers are
// free), then run the dependent FMA chain on arrived data.  Was ~32 exposed
// ~900-cyc latencies (~13 us); now one.
// ---------------------------------------------------------------------------
__global__ __launch_bounds__(256) void p2_kernel(const ushort_t* __restrict__ Dt,
                                                 const float* __restrict__ Bg,
                                                 ushort_t* __restrict__ St) {
    const int chain = blockIdx.x >> 2;
    const int jq = (blockIdx.x & 3) * 16;
    const int tid = threadIdx.x;
    const int jj = jq + (tid >> 4);
    const int ii = (tid & 15) * 4;

    const size_t ebase = (((size_t)chain * NC) * DHEAD + jj) * DHEAD + ii;
    const ushort_t* dp = Dt + ebase;
    ushort_t* sp = St + ebase;
    const size_t cstride = (size_t)DHEAD * DHEAD;

    ushort4 d[NC];
    float eB[NC];
#pragma unroll
    for (int c = 0; c < NC; ++c)
        d[c] = *(const ushort4*)(dp + (size_t)c * cstride);   // all loads in flight
#pragma unroll
    for (int c = 0; c < NC; ++c)
        eB[c] = __expf(Bg[chain * NC + c]);

    float4 S = make_float4(0.f, 0.f, 0.f, 0.f);
#pragma unroll
    for (int c = 0; c < NC; ++c) {
        ushort4 o;
        o.x = f2bf(S.x); o.y = f2bf(S.y); o.z = f2bf(S.z); o.w = f2bf(S.w);
        *(ushort4*)(sp + (size_t)c * cstride) = o;            // state BEFORE chunk c
        S.x = eB[c] * S.x + bf2f(d[c].x);
        S.y = eB[c] * S.y + bf2f(d[c].y);
        S.z = eB[c] * S.z + bf2f(d[c].z);
        S.w = eB[c] * S.w + bf2f(d[c].w);
    }
}

// ---------------------------------------------------------------------------
// Phase 3: Y = diag(e^{b_t}) (Q@St) + (QK^T ⊙ decay ⊙ mask) @ V   -> yb bf16
// V staged feature-major; P~ LDS round-trip wave-private (no barrier).
// ---------------------------------------------------------------------------
__global__ __launch_bounds__(256) void p3_kernel(const ushort_t* __restrict__ qkv,
                                                 const ushort_t* __restrict__ St,
                                                 const float* __restrict__ gate,
                                                 ushort_t* __restrict__ yb) {
    const int tile = blockIdx.x;
    const int chain = tile >> 5;
    const int c = tile & 31;
    const int b = chain >> 4;
    const int h = chain & 15;
    const int tid = threadIdx.x;
    const int w = tid >> 6;
    const int l = tid & 63;

    __shared__ ushort_t Qs[CT * SP];
    __shared__ ushort_t Ks[CT * SP];
    __shared__ ushort_t Vt[DHEAD * SP];   // feature-major
    __shared__ ushort_t Ss[CT * SP];
    __shared__ ushort_t Ps[CT * SP];
    __shared__ float bs[CT];

    {
        const int row = tid >> 2;              // timestep tau
        const int seg = (tid & 3) * 16;
        const size_t grow = ((size_t)(b * SEQ + c * CT + row)) * QKVS + h * DHEAD + seg;
        float4 q0 = *(const float4*)&qkv[grow];
        float4 q1 = *(const float4*)&qkv[grow + 8];
        float4 k0 = *(const float4*)&qkv[grow + 1024];
        float4 k1 = *(const float4*)&qkv[grow + 1024 + 8];
        union { float4 f4[2]; ushort_t us[16]; } uv;
        uv.f4[0] = *(const float4*)&qkv[grow + 2048];
        uv.f4[1] = *(const float4*)&qkv[grow + 2048 + 8];
        const size_t srow = (((size_t)chain * NC + c) * DHEAD + row) * DHEAD + seg;
        float4 s0 = *(const float4*)&St[srow];
        float4 s1 = *(const float4*)&St[srow + 8];
        *(float4*)&Qs[row * SP + seg]     = q0;
        *(float4*)&Qs[row * SP + seg + 8] = q1;
        *(float4*)&Ks[row * SP + seg]     = k0;
        *(float4*)&Ks[row * SP + seg + 8] = k1;
        *(float4*)&Ss[row * SP + seg]     = s0;
        *(float4*)&Ss[row * SP + seg + 8] = s1;
#pragma unroll
        for (int f = 0; f < 16; ++f)
            Vt[(seg + f) * SP + row] = uv.us[f];
    }
    if (tid < 64) {
        float g = gate[((size_t)(b * SEQ + c * CT + tid)) * NHEADS + h];
        float lg = __logf(g);
#pragma unroll
        for (int d = 1; d < 64; d <<= 1) {
            float n = __shfl_up(lg, d, 64);
            if (l >= d) lg += n;
        }
        bs[tid] = lg;
    }
    __syncthreads();

    const int fr = l & 15;
    const int fq = (l >> 4) * 8;
    const int tw = w * 16;

    bf16x8 qa[2];
#pragma unroll
    for (int kc = 0; kc < 2; ++kc)
        qa[kc] = *(const bf16x8*)&Qs[(tw + fr) * SP + kc * 32 + fq];

    f32x4 accA[4], accP[4];
#pragma unroll
    for (int nt = 0; nt < 4; ++nt)
#pragma unroll
        for (int r = 0; r < 4; ++r) { accA[nt][r] = 0.f; accP[nt][r] = 0.f; }

#pragma unroll
    for (int kc = 0; kc < 2; ++kc)
#pragma unroll
        for (int nt = 0; nt < 4; ++nt) {
            bf16x8 sb = *(const bf16x8*)&Ss[(nt * 16 + fr) * SP + kc * 32 + fq];
            accA[nt] = __builtin_amdgcn_mfma_f32_16x16x32_bf16(qa[kc], sb, accA[nt], 0, 0, 0);
            bf16x8 kf = *(const bf16x8*)&Ks[(nt * 16 + fr) * SP + kc * 32 + fq];
            accP[nt] = __builtin_amdgcn_mfma_f32_16x16x32_bf16(qa[kc], kf, accP[nt], 0, 0, 0);
        }

    const int er = (l >> 4) * 4;
    int trow[4];
    float bt[4];
#pragma unroll
    for (int r = 0; r < 4; ++r) { trow[r] = tw + er + r; bt[r] = bs[trow[r]]; }
#pragma unroll
    for (int nt = 0; nt < 4; ++nt) {
        const int tau = nt * 16 + fr;
        const float btau = bs[tau];
#pragma unroll
        for (int r = 0; r < 4; ++r) {
            float f = (tau <= trow[r]) ? __expf(bt[r] - btau) : 0.f;
            Ps[trow[r] * SP + tau] = f2bf(accP[nt][r] * f);
        }
    }
    // no barrier: P~ rows are wave-private (write band == read band per wave)

    f32x4 accY[4];
#pragma unroll
    for (int r = 0; r < 4; ++r) {
        const float eb = __expf(bt[r]);
#pragma unroll
        for (int nt = 0; nt < 4; ++nt) accY[nt][r] = accA[nt][r] * eb;
    }
#pragma unroll
    for (int kc = 0; kc < 2; ++kc) {
        bf16x8 pa = *(const bf16x8*)&Ps[(tw + fr) * SP + kc * 32 + fq];
#pragma unroll
        for (int nt = 0; nt < 4; ++nt) {
            bf16x8 vf = *(const bf16x8*)&Vt[(nt * 16 + fr) * SP + kc * 32 + fq];
            accY[nt] = __builtin_amdgcn_mfma_f32_16x16x32_bf16(pa, vf, accY[nt], 0, 0, 0);
        }
    }

    const size_t ybase = ((size_t)(b * SEQ + c * CT)) * DMODEL + h * DHEAD;
#pragma unroll
    for (int nt = 0; nt < 4; ++nt)
#pragma unroll
        for (int r = 0; r < 4; ++r)
            yb[ybase + (size_t)trow[r] * DMODEL + nt * 16 + fr] = f2bf(accY[nt][r]);
}

// ---------------------------------------------------------------------------
// Host launch
// ---------------------------------------------------------------------------
extern "C" void kernel_launch(void* const* d_in, const int* in_sizes, int n_in,
                              void* d_out, int out_size, void* d_ws, size_t ws_size,
                              hipStream_t stream) {
    const float* x  = (const float*)d_in[0];
    const float* Wq = (const float*)d_in[1];
    const float* Wk = (const float*)d_in[2];
    const float* Wv = (const float*)d_in[3];
    const float* Wo = (const float*)d_in[4];
    const float* Wg = (const float*)d_in[5];
    const float* bg = (const float*)d_in[6];
    float* out = (float*)d_out;

    const size_t elems = (size_t)MTOK * DMODEL;     // 8,388,608
    const size_t stelems = (size_t)NCHAIN * NC * DHEAD * DHEAD;   // 8,388,608

    // layout with aliasing:
    // [xb | St (after p2)] [qkv] [wcat 4224 rows] [gate f32] [Bg f32] [Dt bf16 | yb]
    ushort_t* xb   = (ushort_t*)d_ws;
    ushort_t* St   = xb;                            // alias: xb dead after QKV gemm
    ushort_t* qkv  = xb + elems;                    // [8192][3072]
    ushort_t* wcat = qkv + (size_t)MTOK * QKVS;
    float* gate    = (float*)(wcat + (size_t)WROWS * DMODEL);
    float* Bg      = gate + (size_t)MTOK * NHEADS;
    ushort_t* Dt   = (ushort_t*)(Bg + (size_t)NCHAIN * NC);
    ushort_t* yb   = Dt;                            // alias: Dt dead after p2

    const size_t need = (size_t)((char*)(Dt + stelems) - (char*)d_ws);  // ~90 MB
    if (ws_size < need) return;

    // converts (pure bandwidth)
    cvt_all<<<dim3(MTOK + WROWS), dim3(256), 0, stream>>>(x, Wq, Wk, Wv, Wo, Wg, xb, wcat);

    // fused QKV + gate projection: 25 col tiles (24 qkv + 1 gate), XCD-swizzled
    gemm_bf16<<<dim3(25 * 64), dim3(256), 0, stream>>>(
        xb, wcat, nullptr, qkv, gate, bg, MTOK, QKVS, DMODEL, 3);

    // chunked linear-attention scan
    p1_kernel<<<dim3(NCHAIN * NC), dim3(256), 0, stream>>>(qkv, gate, Dt, Bg);
    p2_kernel<<<dim3(NCHAIN * 4), dim3(256), 0, stream>>>(Dt, Bg, St);
    p3_kernel<<<dim3(NCHAIN * NC), dim3(256), 0, stream>>>(qkv, St, gate, yb);

    // output projection (fp32 out), Wo at wcat rows [3200,4224), XCD-swizzled
    gemm_bf16<<<dim3(8 * 64), dim3(256), 0, stream>>>(
        yb, wcat + (size_t)3200 * DMODEL, out, nullptr, nullptr, nullptr,
        MTOK, DMODEL, DMODEL, 0);
}